// Round 14
// baseline (288.574 us; speedup 1.0000x reference)
//
#include <hip/hip_runtime.h>

typedef unsigned short u16;
typedef unsigned int   u32;
typedef __bf16 bf16x8 __attribute__((ext_vector_type(8)));
typedef float  f32x4  __attribute__((ext_vector_type(4)));

#define S_LEN 4096
#define HIDN  2048
#define NHEAD 16
#define NKVH  4
#define HDIM  128
#define ROTD  64
#define QKVN  3072

__device__ __forceinline__ u16 f2bf_fast(float f) {
  union { __bf16 b; u16 u; } cv; cv.b = (__bf16)f; return cv.u;   // v_cvt hw RNE
}
__device__ __forceinline__ float bf2f(u16 u) {
  union { u32 u; float f; } v; v.u = ((u32)u) << 16; return v.f;
}
__device__ __forceinline__ void gl2lds16(const u16* g, u16* l) {
  __builtin_amdgcn_global_load_lds((const __attribute__((address_space(1))) void*)g,
                                   (__attribute__((address_space(3))) void*)l, 16, 0, 0);
}
__device__ __forceinline__ f32x4 mfma_bf16(bf16x8 a, bf16x8 b, f32x4 c) {
  return __builtin_amdgcn_mfma_f32_16x16x32_bf16(a, b, c, 0, 0, 0);
}
template <int N> __device__ __forceinline__ void vmwait() {
  if constexpr (N == 7)      asm volatile("s_waitcnt vmcnt(7)" ::: "memory");
  else if constexpr (N == 6) asm volatile("s_waitcnt vmcnt(6)" ::: "memory");
  else                       asm volatile("s_waitcnt vmcnt(0)" ::: "memory");
}

// ---------------- fused f32 -> bf16 convert: h | Wq | Wk | Wv (one launch) --
__global__ __launch_bounds__(256) void cvt4_f32_bf16(const float* __restrict__ h,
                                                     const float* __restrict__ Wq,
                                                     const float* __restrict__ Wk,
                                                     const float* __restrict__ Wv,
                                                     u16* __restrict__ hbf,
                                                     u16* __restrict__ wqkv) {
  const int b = blockIdx.x;
  const float* src; u16* dst;
  if (b < 4096)      { src = h  + (size_t)b * 2048;           dst = hbf  + (size_t)b * 2048; }
  else if (b < 6144) { src = Wq + (size_t)(b - 4096) * 2048;  dst = wqkv + (size_t)(b - 4096) * 2048; }
  else if (b < 6656) { src = Wk + (size_t)(b - 6144) * 2048;  dst = wqkv + 4194304u + (size_t)(b - 6144) * 2048; }
  else               { src = Wv + (size_t)(b - 6656) * 2048;  dst = wqkv + 5242880u + (size_t)(b - 6656) * 2048; }
  size_t i = (size_t)threadIdx.x * 8;
  float4 a = *(const float4*)(src + i);
  float4 c = *(const float4*)(src + i + 4);
  uint4 r;
  r.x = (u32)f2bf_fast(a.x) | ((u32)f2bf_fast(a.y) << 16);
  r.y = (u32)f2bf_fast(a.z) | ((u32)f2bf_fast(a.w) << 16);
  r.z = (u32)f2bf_fast(c.x) | ((u32)f2bf_fast(c.y) << 16);
  r.w = (u32)f2bf_fast(c.z) | ((u32)f2bf_fast(c.w) << 16);
  *(uint4*)(dst + i) = r;
}

// ---------------- plain f32 -> bf16 convert (Wo, after qkvb is dead) --------
__global__ __launch_bounds__(256) void cvt_f32_bf16(const float* __restrict__ in,
                                                    u16* __restrict__ out) {
  size_t i = ((size_t)blockIdx.x * 256 + threadIdx.x) * 8;
  float4 a = *(const float4*)(in + i);
  float4 b = *(const float4*)(in + i + 4);
  uint4 r;
  r.x = (u32)f2bf_fast(a.x) | ((u32)f2bf_fast(a.y) << 16);
  r.y = (u32)f2bf_fast(a.z) | ((u32)f2bf_fast(a.w) << 16);
  r.z = (u32)f2bf_fast(b.x) | ((u32)f2bf_fast(b.y) << 16);
  r.w = (u32)f2bf_fast(b.z) | ((u32)f2bf_fast(b.w) << 16);
  *(uint4*)(out + i) = r;
}

// ---------------- GEMM v3: C[M,N] = A[M,K]*B[N,K]^T (unchanged from R13) ----
template <int BN, int NB, bool BF16OUT>
__global__ __launch_bounds__(512, 2) void gemm_big(const u16* __restrict__ A,
                                                   const u16* __restrict__ Bm,
                                                   void* __restrict__ Cp,
                                                   int M, int N, int K) {
  constexpr int WNC = BN / 4;
  constexpr int NF  = WNC / 16;
  constexpr int ASZ = 256 * 128;
  constexpr int BUF = ASZ + BN * 128;
  constexpr int LOADS = 4 + NB;
  __shared__ __align__(1024) char lds[2 * BUF];

  const int tid = threadIdx.x, wave = tid >> 6, lane = tid & 63;
  const int wm = wave >> 2, wn = wave & 3;
  const int row0 = blockIdx.x * 256, col0 = blockIdx.y * BN;
  const int l8 = lane >> 3, l7 = lane & 7;
  const int T = K >> 6;

  const u16* gA[4]; const u16* gB[NB];
  u16* ldsA[4]; u16* ldsB[NB];
  #pragma unroll
  for (int i = 0; i < 4; ++i) {
    gA[i]  = A + (size_t)(row0 + wave * 32 + i * 8 + l8) * K + (l7 ^ l8) * 8;
    ldsA[i] = (u16*)(lds + wave * 4096 + i * 1024);
  }
  #pragma unroll
  for (int i = 0; i < NB; ++i) {
    gB[i]  = Bm + (size_t)(col0 + wave * (BN / 8) + i * 8 + l8) * K + (l7 ^ l8) * 8;
    ldsB[i] = (u16*)(lds + ASZ + wave * (BN * 16) + i * 1024);
  }
  auto stage = [&](int buf, int t) {
    const size_t ko = (size_t)t * 64;
    #pragma unroll
    for (int i = 0; i < 4; ++i)
      gl2lds16(gA[i] + ko, (u16*)((char*)ldsA[i] + buf * BUF));
    #pragma unroll
    for (int i = 0; i < NB; ++i)
      gl2lds16(gB[i] + ko, (u16*)((char*)ldsB[i] + buf * BUF));
  };

  const int colx0 = (((lane >> 4))     ^ l7) * 16;
  const int colx1 = ((4 + (lane >> 4)) ^ l7) * 16;
  const char* aB = lds + (wm * 128 + (lane & 15)) * 128;
  const char* bB = lds + ASZ + (wn * WNC + (lane & 15)) * 128;

  f32x4 acc[8][NF];
  #pragma unroll
  for (int i = 0; i < 8; ++i)
    #pragma unroll
    for (int j = 0; j < NF; ++j) { f32x4 z = {0.f,0.f,0.f,0.f}; acc[i][j] = z; }

  stage(0, 0);
  stage(1, 1);
  vmwait<LOADS>();
  __builtin_amdgcn_s_barrier();

  for (int t = 0; t < T; ++t) {
    const int bo = (t & 1) * BUF;
    #pragma unroll
    for (int kh = 0; kh < 2; ++kh) {
      const int cx = kh ? colx1 : colx0;
      bf16x8 bfr[NF];
      #pragma unroll
      for (int nf = 0; nf < NF; ++nf)
        bfr[nf] = *(const bf16x8*)(bB + bo + nf * 2048 + cx);
      #pragma unroll
      for (int mh = 0; mh < 2; ++mh) {
        bf16x8 af[4];
        #pragma unroll
        for (int mf = 0; mf < 4; ++mf)
          af[mf] = *(const bf16x8*)(aB + bo + mh * 8192 + mf * 2048 + cx);
        __builtin_amdgcn_s_barrier();
        asm volatile("s_waitcnt lgkmcnt(0)" ::: "memory");
        __builtin_amdgcn_s_setprio(1);
        #pragma unroll
        for (int mf = 0; mf < 4; ++mf)
          #pragma unroll
          for (int nf = 0; nf < NF; ++nf)
            acc[mh * 4 + mf][nf] = mfma_bf16(af[mf], bfr[nf], acc[mh * 4 + mf][nf]);
        __builtin_amdgcn_s_setprio(0);
        __builtin_amdgcn_s_barrier();
      }
    }
    if (t + 2 < T) stage(t & 1, t + 2);
    if (t + 1 < T) {
      if (t + 2 < T) vmwait<LOADS>();
      else           vmwait<0>();
      __builtin_amdgcn_s_barrier();
    }
  }

  const int mwv = row0 + wm * 128, nwv = col0 + wn * WNC;
  #pragma unroll
  for (int mf8 = 0; mf8 < 8; ++mf8)
    #pragma unroll
    for (int nf = 0; nf < NF; ++nf)
      #pragma unroll
      for (int r = 0; r < 4; ++r) {
        int m = mwv + (mf8 >> 2) * 64 + (mf8 & 3) * 16 + (lane >> 4) * 4 + r;
        int n = nwv + nf * 16 + (lane & 15);
        float v = acc[mf8][nf][r];
        if (BF16OUT) ((u16*)Cp)[(size_t)m * N + n] = f2bf_fast(v);
        else         ((float*)Cp)[(size_t)m * N + n] = v;
      }
}

// ---------------- fused RMSNorm (full row) + partial RoPE + head transpose --
__global__ __launch_bounds__(256) void norm_rope(const u16* __restrict__ qkv,
                                                 const float* __restrict__ cosb,
                                                 const float* __restrict__ sinb,
                                                 const float* __restrict__ qw,
                                                 const float* __restrict__ kw,
                                                 u16* __restrict__ Qo,
                                                 u16* __restrict__ Ko) {
  const int s = blockIdx.x, t = threadIdx.x;
  const int wave = t >> 6, lane = t & 63;
  const float SL = 0.08838834764831845f * 1.4426950408889634f;  // SCALE*log2e
  __shared__ float rowbuf[HIDN];
  __shared__ float red[4];
  const u16* base = qkv + (size_t)s * QKVN;

  float x[8];
  {
    uint4 v = *(const uint4*)(base + t * 8);
    u32 w4[4] = {v.x, v.y, v.z, v.w};
    #pragma unroll
    for (int j = 0; j < 4; ++j) {
      x[2*j]   = bf2f((u16)(w4[j] & 0xffffu));
      x[2*j+1] = bf2f((u16)(w4[j] >> 16));
    }
  }
  float ss = 0.f;
  #pragma unroll
  for (int j = 0; j < 8; ++j) ss += x[j] * x[j];
  #pragma unroll
  for (int m = 1; m < 64; m <<= 1) ss += __shfl_xor(ss, m);
  if (lane == 0) red[wave] = ss;
  __syncthreads();
  float rs = rsqrtf((red[0]+red[1]+red[2]+red[3]) * (1.0f / HIDN) + 1e-6f);
  #pragma unroll
  for (int j = 0; j < 8; ++j) rowbuf[t*8 + j] = x[j] * rs * qw[t*8 + j];
  __syncthreads();
  {
    int i0 = t * 8, d0 = i0 & (HDIM - 1), hh = i0 >> 7;
    float o[8];
    if (d0 < ROTD) {
      #pragma unroll
      for (int j = 0; j < 8; ++j) {
        int d = d0 + j;
        float rot = (d < 32) ? -rowbuf[i0 + j + 32] : rowbuf[i0 + j - 32];
        o[j] = rowbuf[i0 + j] * cosb[s*ROTD + d] + rot * sinb[s*ROTD + d];
      }
    } else {
      #pragma unroll
      for (int j = 0; j < 8; ++j) o[j] = rowbuf[i0 + j];
    }
    uint4 r;
    r.x = (u32)f2bf_fast(o[0]*SL) | ((u32)f2bf_fast(o[1]*SL) << 16);
    r.y = (u32)f2bf_fast(o[2]*SL) | ((u32)f2bf_fast(o[3]*SL) << 16);
    r.z = (u32)f2bf_fast(o[4]*SL) | ((u32)f2bf_fast(o[5]*SL) << 16);
    r.w = (u32)f2bf_fast(o[6]*SL) | ((u32)f2bf_fast(o[7]*SL) << 16);
    *(uint4*)(Qo + ((size_t)hh * S_LEN + s) * HDIM + d0) = r;
  }

  const u16* kbase = base + HIDN;
  float y0, y1;
  { u32 v = *(const u32*)(kbase + t * 2); y0 = bf2f((u16)(v & 0xffffu)); y1 = bf2f((u16)(v >> 16)); }
  float ss2 = y0*y0 + y1*y1;
  #pragma unroll
  for (int m = 1; m < 64; m <<= 1) ss2 += __shfl_xor(ss2, m);
  __syncthreads();
  if (lane == 0) red[wave] = ss2;
  __syncthreads();
  float rs2 = rsqrtf((red[0]+red[1]+red[2]+red[3]) * (1.0f / 512.0f) + 1e-6f);
  rowbuf[t*2]     = y0 * rs2 * kw[t*2];
  rowbuf[t*2 + 1] = y1 * rs2 * kw[t*2 + 1];
  __syncthreads();
  {
    int i0 = t * 2, d0 = i0 & (HDIM - 1), hh = i0 >> 7;
    float o0, o1;
    if (d0 < ROTD) {
      float r0 = (d0 < 32) ? -rowbuf[i0 + 32] : rowbuf[i0 - 32];
      float r1 = (d0 + 1 < 32) ? -rowbuf[i0 + 1 + 32] : rowbuf[i0 + 1 - 32];
      o0 = rowbuf[i0]     * cosb[s*ROTD + d0]     + r0 * sinb[s*ROTD + d0];
      o1 = rowbuf[i0 + 1] * cosb[s*ROTD + d0 + 1] + r1 * sinb[s*ROTD + d0 + 1];
    } else { o0 = rowbuf[i0]; o1 = rowbuf[i0 + 1]; }
    u32 r = (u32)f2bf_fast(o0) | ((u32)f2bf_fast(o1) << 16);
    *(u32*)(Ko + ((size_t)hh * S_LEN + s) * HDIM + d0) = r;
  }
}

// ---------------- V transpose: qkv[S][3072] v-cols -> Vt[NKV][HD][S] --------
__global__ __launch_bounds__(256) void vtrans(const u16* __restrict__ qkv,
                                              u16* __restrict__ Vt) {
  const int sb = blockIdx.x * 64, db = blockIdx.y * 64, kvh = blockIdx.z;
  __shared__ u16 tile[64][72];
  const int t = threadIdx.x;
  {
    int r = t >> 2, cc = (t & 3) * 16;
    const u16* src = qkv + (size_t)(sb + r) * QKVN + 2560 + kvh * HDIM + db + cc;
    *(uint4*)&tile[r][cc]     = *(const uint4*)(src);
    *(uint4*)&tile[r][cc + 8] = *(const uint4*)(src + 8);
  }
  __syncthreads();
  {
    int d = t >> 2, sc = (t & 3) * 16;
    u16 tmp[16];
    #pragma unroll
    for (int j = 0; j < 16; ++j) tmp[j] = tile[sc + j][d];
    u16* dst = Vt + ((size_t)kvh * HDIM + db + d) * S_LEN + sb + sc;
    *(uint4*)dst       = *(uint4*)&tmp[0];
    *(uint4*)(dst + 8) = *(uint4*)&tmp[8];
  }
}

// ---------------- causal GQA flash attention (v8: V direct from L2) ---------
// v7 quadrant-wave geometry (512 blocks, XCD affinity, mirror jobs, dbuf K)
// with V read DIRECTLY from global (L2-resident by XCD affinity: 2MB K+V per
// XCD L2, proven by R8's FETCH drop). Eliminates V staging (4 gl2lds) and V
// LDS reads (8 b128) per wave-tile: LDS traffic 28 -> 16 KB/wave-tile.
// vf loads issued at tile top (issue-early, T14): QK^T+softmax (~600cyc)
// covers the ~200cyc L2 hit; compiler inserts the vmcnt before PV use.
// Vs LDS becomes the dedicated cross-kv-half combine scratch (72KB total).
__global__ __launch_bounds__(256, 2) void attn_fwd(const u16* __restrict__ Q,
                                                   const u16* __restrict__ K,
                                                   const u16* __restrict__ Vt,
                                                   u16* __restrict__ O) {
  const int n    = blockIdx.x;
  const int slot = n & 7, kq = n >> 3;             // kq 0..63
  const int kvh  = slot >> 1;                      // XCD affinity: 2 slots/kvh
  const int h    = kvh * 4 + (slot & 1) * 2 + (kq & 1);
  const int p    = kq >> 1;                        // mirror-pair index 0..31
  const int tid = threadIdx.x, wave = tid >> 6, lane = tid & 63;
  const int rh   = wave & 1;                       // row-half of the q tile
  const int kvh2 = wave >> 1;                      // kv-half of the kv tile
  __shared__ u16 Ks[2][64][128];                   // 32KB (dbuf K)
  __shared__ f32x4 scrb[2][1024];                  // 32KB combine scratch
  __shared__ u16 Ps[2][32][64];                    //  8KB (per row-half)

  // K staging bases (pre-swizzled global source)
  const u16* gKb[4];
  #pragma unroll
  for (int i = 0; i < 4; ++i) {
    int cc = wave * 4 + i;
    int rk = cc * 4 + (lane >> 4);
    gKb[i] = K + ((size_t)kvh * S_LEN + rk) * HDIM + ((lane & 15) ^ (rk & 7)) * 8;
  }
  auto stage = [&](int buf, int kvb) {
    #pragma unroll
    for (int i = 0; i < 4; ++i) {
      int cc = wave * 4 + i;
      gl2lds16(gKb[i] + (size_t)kvb * HDIM, &Ks[buf][cc * 4][0]);
    }
  };

  // V fragment base: lane reads Vt[kvh][nf2*16+(lane&15)][kvb + kvh2*32 + (lane>>4)*8]
  const u16* gVt = Vt + ((size_t)kvh * HDIM + (lane & 15)) * S_LEN
                   + kvh2 * 32 + (lane >> 4) * 8;

  // swizzled K/P LDS read offsets ((row&7) == (lane&7) for every fragment)
  int offv[4];
  #pragma unroll
  for (int kk = 0; kk < 4; ++kk)
    offv[kk] = (kk * 64 + (lane >> 4) * 16) ^ ((lane & 7) << 4);
  const char* ksB = (const char*)Ks + kvh2 * 8192 + (lane & 15) * 256;
  const char* psB = (const char*)Ps + rh * 4096 + (lane & 15) * 128;
  char*       pwB = (char*)Ps + rh * 4096;
  const int   lx2 = (lane & 15) * 2;
  const int   vko = offv[kvh2];                    // pf col offset (kv half)

  stage(0, 0);                                     // prologue: job0 tile0
  __syncthreads();
  int cur = 0;

  for (int job = 0; job < 2; ++job) {
    const int qb = job ? (63 - p) : p;
    const int ntiles = qb + 1;
    const int qg0 = qb * 64 + rh * 32 + (lane >> 4) * 4;  // + qm*16 + r = q row

    bf16x8 qf[2][4];
    #pragma unroll
    for (int qm = 0; qm < 2; ++qm) {
      const u16* qptr = Q + ((size_t)h * S_LEN + qb * 64 + rh * 32 + qm * 16 + (lane & 15)) * HDIM
                        + (lane >> 4) * 8;
      #pragma unroll
      for (int kk = 0; kk < 4; ++kk) qf[qm][kk] = *(const bf16x8*)(qptr + kk * 32);
    }

    float lsum[2][4];
    #pragma unroll
    for (int qm = 0; qm < 2; ++qm)
      #pragma unroll
      for (int r = 0; r < 4; ++r) lsum[qm][r] = 0.f;
    f32x4 o[2][8];
    #pragma unroll
    for (int qm = 0; qm < 2; ++qm)
      #pragma unroll
      for (int i = 0; i < 8; ++i) { f32x4 z = {0.f,0.f,0.f,0.f}; o[qm][i] = z; }

    for (int kt = 0; kt < ntiles; ++kt) {
      const int kvb = kt * 64;
      const bool diag = (kt == ntiles - 1);
      const bool act  = !(diag && kvh2 == 1 && rh == 0);

      // ---- issue V fragment loads FIRST (L2-resident; lands under QK^T) ----
      bf16x8 vf[8];
      if (act) {
        const u16* gv = gVt + kvb;
        #pragma unroll
        for (int nf2 = 0; nf2 < 8; ++nf2)
          vf[nf2] = *(const bf16x8*)(gv + (size_t)nf2 * 16 * S_LEN);
      }

      // ---- prefetch next K tile ----
      if (kt + 1 < ntiles)      stage(cur ^ 1, (kt + 1) * 64);
      else if (job == 0)        stage(cur ^ 1, 0);

      const int bufo = cur << 14;

      if (act) {
        // ---- QK^T: 8 kf reads feed 16 MFMAs (2 M-frags each) ----
        f32x4 sc[2][2];
        #pragma unroll
        for (int qm = 0; qm < 2; ++qm)
          #pragma unroll
          for (int i = 0; i < 2; ++i) { f32x4 z = {0.f,0.f,0.f,0.f}; sc[qm][i] = z; }
        __builtin_amdgcn_s_setprio(1);
        #pragma unroll
        for (int kk = 0; kk < 4; ++kk)
          #pragma unroll
          for (int nf = 0; nf < 2; ++nf) {
            bf16x8 kf = *(const bf16x8*)(ksB + bufo + nf * 4096 + offv[kk]);
            sc[0][nf] = mfma_bf16(qf[0][kk], kf, sc[0][nf]);
            sc[1][nf] = mfma_bf16(qf[1][kk], kf, sc[1][nf]);
          }
        __builtin_amdgcn_s_setprio(0);

        // ---- static-max softmax: e = 2^s; zero-mask on diagonal tile ----
        if (diag) {
          #pragma unroll
          for (int qm = 0; qm < 2; ++qm)
            #pragma unroll
            for (int nf = 0; nf < 2; ++nf) {
              int col = kvb + kvh2 * 32 + nf * 16 + (lane & 15);
              #pragma unroll
              for (int r = 0; r < 4; ++r) {
                float e = __builtin_amdgcn_exp2f(sc[qm][nf][r]);
                e = (col <= qg0 + qm * 16 + r) ? e : 0.f;
                sc[qm][nf][r] = e;
                lsum[qm][r] += e;
              }
            }
        } else {
          #pragma unroll
          for (int qm = 0; qm < 2; ++qm)
            #pragma unroll
            for (int nf = 0; nf < 2; ++nf)
              #pragma unroll
              for (int r = 0; r < 4; ++r) {
                float e = __builtin_amdgcn_exp2f(sc[qm][nf][r]);
                sc[qm][nf][r] = e;
                lsum[qm][r] += e;
              }
        }

        // ---- P write (wave-private quadrant, swizzled) ----
        #pragma unroll
        for (int qm = 0; qm < 2; ++qm)
          #pragma unroll
          for (int nf = 0; nf < 2; ++nf)
            #pragma unroll
            for (int r = 0; r < 4; ++r) {
              int prow = qm * 16 + (lane >> 4) * 4 + r;
              int bcol = (kvh2 * 64 + nf * 32 + lx2) ^ ((prow & 7) << 4);
              *(u16*)(pwB + prow * 128 + bcol) = f2bf_fast(sc[qm][nf][r]);
            }

        // ---- PV: vf from registers (L2), pf from LDS ----
        bf16x8 pf0 = *(const bf16x8*)(psB + vko);
        bf16x8 pf1 = *(const bf16x8*)(psB + 2048 + vko);
        __builtin_amdgcn_s_setprio(1);
        #pragma unroll
        for (int nf2 = 0; nf2 < 8; ++nf2) {
          o[0][nf2] = mfma_bf16(pf0, vf[nf2], o[0][nf2]);
          o[1][nf2] = mfma_bf16(pf1, vf[nf2], o[1][nf2]);
        }
        __builtin_amdgcn_s_setprio(0);
      }

      __syncthreads();                             // staged K ready, cur reusable
      cur ^= 1;
    }

    // ---- cross-kv-half combine (partials exactly additive) ----
    {
      f32x4* scr = &scrb[rh][0];
      float* lsc = (float*)Ps;
      if (kvh2 == 1) {
        #pragma unroll
        for (int qm = 0; qm < 2; ++qm)
          #pragma unroll
          for (int nf2 = 0; nf2 < 8; ++nf2)
            scr[(qm * 8 + nf2) * 64 + lane] = o[qm][nf2];
        #pragma unroll
        for (int qm = 0; qm < 2; ++qm)
          #pragma unroll
          for (int r = 0; r < 4; ++r)
            lsc[rh * 512 + (qm * 4 + r) * 64 + lane] = lsum[qm][r];
      }
      __syncthreads();
      if (kvh2 == 0) {
        #pragma unroll
        for (int qm = 0; qm < 2; ++qm)
          #pragma unroll
          for (int nf2 = 0; nf2 < 8; ++nf2)
            o[qm][nf2] += scr[(qm * 8 + nf2) * 64 + lane];
        #pragma unroll
        for (int qm = 0; qm < 2; ++qm)
          #pragma unroll
          for (int r = 0; r < 4; ++r)
            lsum[qm][r] += lsc[rh * 512 + (qm * 4 + r) * 64 + lane];

        #pragma unroll
        for (int qm = 0; qm < 2; ++qm)
          #pragma unroll
          for (int r = 0; r < 4; ++r) {
            float lt = lsum[qm][r];
            #pragma unroll
            for (int m = 1; m < 16; m <<= 1) lt += __shfl_xor(lt, m);
            float inv = 1.f / lt;
            int srow = qg0 + qm * 16 + r;
            #pragma unroll
            for (int nf2 = 0; nf2 < 8; ++nf2) {
              int col = h * HDIM + nf2 * 16 + (lane & 15);
              O[(size_t)srow * HIDN + col] = f2bf_fast(o[qm][nf2][r] * inv);
            }
          }
      }
      __syncthreads();                             // lsc/Ps safe before job1
    }
  }
}

// ---------------- launch -----------------------------------------------------
extern "C" void kernel_launch(void* const* d_in, const int* in_sizes, int n_in,
                              void* d_out, int out_size, void* d_ws, size_t ws_size,
                              hipStream_t stream) {
  (void)in_sizes; (void)n_in; (void)out_size; (void)ws_size;
  const float* h    = (const float*)d_in[0];
  const float* cosb = (const float*)d_in[1];
  const float* sinb = (const float*)d_in[2];
  const float* Wq   = (const float*)d_in[3];
  const float* Wk   = (const float*)d_in[4];
  const float* Wv   = (const float*)d_in[5];
  const float* Wo   = (const float*)d_in[6];
  const float* qw   = (const float*)d_in[7];
  const float* kw   = (const float*)d_in[8];
  float* out = (float*)d_out;

  char* ws = (char*)d_ws;
  u16* hbf  = (u16*)(ws);
  u16* Kb   = (u16*)(ws + (16u << 20));
  u16* Vtb  = (u16*)(ws + (20u << 20));
  u16* wqkv = (u16*)(ws + (24u << 20));
  u16* Qb   = (u16*)(ws + (24u << 20));
  u16* qkvb = (u16*)(ws + (40u << 20));
  u16* wob  = (u16*)(ws + (40u << 20));

  cvt4_f32_bf16<<<7168, 256, 0, stream>>>(h, Wq, Wk, Wv, hbf, wqkv);

  gemm_big<192, 3, true><<<dim3(16, 16), 512, 0, stream>>>(hbf, wqkv, qkvb,
                                                           4096, 3072, 2048);

  norm_rope<<<4096, 256, 0, stream>>>(qkvb, cosb, sinb, qw, kw, Qb, Kb);
  vtrans<<<dim3(64, 2, 4), 256, 0, stream>>>(qkvb, Vtb);

  cvt_f32_bf16<<<2048, 256, 0, stream>>>(Wo, wob);

  attn_fwd<<<dim3(512), 256, 0, stream>>>(Qb, Kb, Vtb, hbf);

  gemm_big<128, 2, false><<<dim3(16, 16), 512, 0, stream>>>(hbf, wob, out,
                                                            4096, 2048, 2048);
}

// Round 15
// 240.646 us; speedup vs baseline: 1.1992x; 1.1992x over previous
//
#include <hip/hip_runtime.h>

typedef unsigned short u16;
typedef unsigned int   u32;
typedef __bf16 bf16x8 __attribute__((ext_vector_type(8)));
typedef float  f32x4  __attribute__((ext_vector_type(4)));

#define S_LEN 4096
#define HIDN  2048
#define NHEAD 16
#define NKVH  4
#define HDIM  128
#define ROTD  64
#define QKVN  3072

__device__ __forceinline__ u16 f2bf_fast(float f) {
  union { __bf16 b; u16 u; } cv; cv.b = (__bf16)f; return cv.u;   // v_cvt hw RNE
}
__device__ __forceinline__ float bf2f(u16 u) {
  union { u32 u; float f; } v; v.u = ((u32)u) << 16; return v.f;
}
__device__ __forceinline__ void gl2lds16(const u16* g, u16* l) {
  __builtin_amdgcn_global_load_lds((const __attribute__((address_space(1))) void*)g,
                                   (__attribute__((address_space(3))) void*)l, 16, 0, 0);
}
__device__ __forceinline__ f32x4 mfma_bf16(bf16x8 a, bf16x8 b, f32x4 c) {
  return __builtin_amdgcn_mfma_f32_16x16x32_bf16(a, b, c, 0, 0, 0);
}
template <int N> __device__ __forceinline__ void vmwait() {
  if constexpr (N == 7)      asm volatile("s_waitcnt vmcnt(7)" ::: "memory");
  else if constexpr (N == 6) asm volatile("s_waitcnt vmcnt(6)" ::: "memory");
  else                       asm volatile("s_waitcnt vmcnt(0)" ::: "memory");
}

// ---------------- fused f32 -> bf16 convert: h | Wq | Wk | Wv (one launch) --
__global__ __launch_bounds__(256) void cvt4_f32_bf16(const float* __restrict__ h,
                                                     const float* __restrict__ Wq,
                                                     const float* __restrict__ Wk,
                                                     const float* __restrict__ Wv,
                                                     u16* __restrict__ hbf,
                                                     u16* __restrict__ wqkv) {
  const int b = blockIdx.x;
  const float* src; u16* dst;
  if (b < 4096)      { src = h  + (size_t)b * 2048;           dst = hbf  + (size_t)b * 2048; }
  else if (b < 6144) { src = Wq + (size_t)(b - 4096) * 2048;  dst = wqkv + (size_t)(b - 4096) * 2048; }
  else if (b < 6656) { src = Wk + (size_t)(b - 6144) * 2048;  dst = wqkv + 4194304u + (size_t)(b - 6144) * 2048; }
  else               { src = Wv + (size_t)(b - 6656) * 2048;  dst = wqkv + 5242880u + (size_t)(b - 6656) * 2048; }
  size_t i = (size_t)threadIdx.x * 8;
  float4 a = *(const float4*)(src + i);
  float4 c = *(const float4*)(src + i + 4);
  uint4 r;
  r.x = (u32)f2bf_fast(a.x) | ((u32)f2bf_fast(a.y) << 16);
  r.y = (u32)f2bf_fast(a.z) | ((u32)f2bf_fast(a.w) << 16);
  r.z = (u32)f2bf_fast(c.x) | ((u32)f2bf_fast(c.y) << 16);
  r.w = (u32)f2bf_fast(c.z) | ((u32)f2bf_fast(c.w) << 16);
  *(uint4*)(dst + i) = r;
}

// ---------------- plain f32 -> bf16 convert (Wo, after qkvb is dead) --------
__global__ __launch_bounds__(256) void cvt_f32_bf16(const float* __restrict__ in,
                                                    u16* __restrict__ out) {
  size_t i = ((size_t)blockIdx.x * 256 + threadIdx.x) * 8;
  float4 a = *(const float4*)(in + i);
  float4 b = *(const float4*)(in + i + 4);
  uint4 r;
  r.x = (u32)f2bf_fast(a.x) | ((u32)f2bf_fast(a.y) << 16);
  r.y = (u32)f2bf_fast(a.z) | ((u32)f2bf_fast(a.w) << 16);
  r.z = (u32)f2bf_fast(b.x) | ((u32)f2bf_fast(b.y) << 16);
  r.w = (u32)f2bf_fast(b.z) | ((u32)f2bf_fast(b.w) << 16);
  *(uint4*)(out + i) = r;
}

// ---------------- GEMM v3: C[M,N] = A[M,K]*B[N,K]^T (unchanged) -------------
template <int BN, int NB, bool BF16OUT>
__global__ __launch_bounds__(512, 2) void gemm_big(const u16* __restrict__ A,
                                                   const u16* __restrict__ Bm,
                                                   void* __restrict__ Cp,
                                                   int M, int N, int K) {
  constexpr int WNC = BN / 4;
  constexpr int NF  = WNC / 16;
  constexpr int ASZ = 256 * 128;
  constexpr int BUF = ASZ + BN * 128;
  constexpr int LOADS = 4 + NB;
  __shared__ __align__(1024) char lds[2 * BUF];

  const int tid = threadIdx.x, wave = tid >> 6, lane = tid & 63;
  const int wm = wave >> 2, wn = wave & 3;
  const int row0 = blockIdx.x * 256, col0 = blockIdx.y * BN;
  const int l8 = lane >> 3, l7 = lane & 7;
  const int T = K >> 6;

  const u16* gA[4]; const u16* gB[NB];
  u16* ldsA[4]; u16* ldsB[NB];
  #pragma unroll
  for (int i = 0; i < 4; ++i) {
    gA[i]  = A + (size_t)(row0 + wave * 32 + i * 8 + l8) * K + (l7 ^ l8) * 8;
    ldsA[i] = (u16*)(lds + wave * 4096 + i * 1024);
  }
  #pragma unroll
  for (int i = 0; i < NB; ++i) {
    gB[i]  = Bm + (size_t)(col0 + wave * (BN / 8) + i * 8 + l8) * K + (l7 ^ l8) * 8;
    ldsB[i] = (u16*)(lds + ASZ + wave * (BN * 16) + i * 1024);
  }
  auto stage = [&](int buf, int t) {
    const size_t ko = (size_t)t * 64;
    #pragma unroll
    for (int i = 0; i < 4; ++i)
      gl2lds16(gA[i] + ko, (u16*)((char*)ldsA[i] + buf * BUF));
    #pragma unroll
    for (int i = 0; i < NB; ++i)
      gl2lds16(gB[i] + ko, (u16*)((char*)ldsB[i] + buf * BUF));
  };

  const int colx0 = (((lane >> 4))     ^ l7) * 16;
  const int colx1 = ((4 + (lane >> 4)) ^ l7) * 16;
  const char* aB = lds + (wm * 128 + (lane & 15)) * 128;
  const char* bB = lds + ASZ + (wn * WNC + (lane & 15)) * 128;

  f32x4 acc[8][NF];
  #pragma unroll
  for (int i = 0; i < 8; ++i)
    #pragma unroll
    for (int j = 0; j < NF; ++j) { f32x4 z = {0.f,0.f,0.f,0.f}; acc[i][j] = z; }

  stage(0, 0);
  stage(1, 1);
  vmwait<LOADS>();
  __builtin_amdgcn_s_barrier();

  for (int t = 0; t < T; ++t) {
    const int bo = (t & 1) * BUF;
    #pragma unroll
    for (int kh = 0; kh < 2; ++kh) {
      const int cx = kh ? colx1 : colx0;
      bf16x8 bfr[NF];
      #pragma unroll
      for (int nf = 0; nf < NF; ++nf)
        bfr[nf] = *(const bf16x8*)(bB + bo + nf * 2048 + cx);
      #pragma unroll
      for (int mh = 0; mh < 2; ++mh) {
        bf16x8 af[4];
        #pragma unroll
        for (int mf = 0; mf < 4; ++mf)
          af[mf] = *(const bf16x8*)(aB + bo + mh * 8192 + mf * 2048 + cx);
        __builtin_amdgcn_s_barrier();
        asm volatile("s_waitcnt lgkmcnt(0)" ::: "memory");
        __builtin_amdgcn_s_setprio(1);
        #pragma unroll
        for (int mf = 0; mf < 4; ++mf)
          #pragma unroll
          for (int nf = 0; nf < NF; ++nf)
            acc[mh * 4 + mf][nf] = mfma_bf16(af[mf], bfr[nf], acc[mh * 4 + mf][nf]);
        __builtin_amdgcn_s_setprio(0);
        __builtin_amdgcn_s_barrier();
      }
    }
    if (t + 2 < T) stage(t & 1, t + 2);
    if (t + 1 < T) {
      if (t + 2 < T) vmwait<LOADS>();
      else           vmwait<0>();
      __builtin_amdgcn_s_barrier();
    }
  }

  const int mwv = row0 + wm * 128, nwv = col0 + wn * WNC;
  #pragma unroll
  for (int mf8 = 0; mf8 < 8; ++mf8)
    #pragma unroll
    for (int nf = 0; nf < NF; ++nf)
      #pragma unroll
      for (int r = 0; r < 4; ++r) {
        int m = mwv + (mf8 >> 2) * 64 + (mf8 & 3) * 16 + (lane >> 4) * 4 + r;
        int n = nwv + nf * 16 + (lane & 15);
        float v = acc[mf8][nf][r];
        if (BF16OUT) ((u16*)Cp)[(size_t)m * N + n] = f2bf_fast(v);
        else         ((float*)Cp)[(size_t)m * N + n] = v;
      }
}

// ---------------- fused RMSNorm (full row) + partial RoPE + head transpose --
__global__ __launch_bounds__(256) void norm_rope(const u16* __restrict__ qkv,
                                                 const float* __restrict__ cosb,
                                                 const float* __restrict__ sinb,
                                                 const float* __restrict__ qw,
                                                 const float* __restrict__ kw,
                                                 u16* __restrict__ Qo,
                                                 u16* __restrict__ Ko) {
  const int s = blockIdx.x, t = threadIdx.x;
  const int wave = t >> 6, lane = t & 63;
  const float SL = 0.08838834764831845f * 1.4426950408889634f;  // SCALE*log2e
  __shared__ float rowbuf[HIDN];
  __shared__ float red[4];
  const u16* base = qkv + (size_t)s * QKVN;

  float x[8];
  {
    uint4 v = *(const uint4*)(base + t * 8);
    u32 w4[4] = {v.x, v.y, v.z, v.w};
    #pragma unroll
    for (int j = 0; j < 4; ++j) {
      x[2*j]   = bf2f((u16)(w4[j] & 0xffffu));
      x[2*j+1] = bf2f((u16)(w4[j] >> 16));
    }
  }
  float ss = 0.f;
  #pragma unroll
  for (int j = 0; j < 8; ++j) ss += x[j] * x[j];
  #pragma unroll
  for (int m = 1; m < 64; m <<= 1) ss += __shfl_xor(ss, m);
  if (lane == 0) red[wave] = ss;
  __syncthreads();
  float rs = rsqrtf((red[0]+red[1]+red[2]+red[3]) * (1.0f / HIDN) + 1e-6f);
  #pragma unroll
  for (int j = 0; j < 8; ++j) rowbuf[t*8 + j] = x[j] * rs * qw[t*8 + j];
  __syncthreads();
  {
    int i0 = t * 8, d0 = i0 & (HDIM - 1), hh = i0 >> 7;
    float o[8];
    if (d0 < ROTD) {
      #pragma unroll
      for (int j = 0; j < 8; ++j) {
        int d = d0 + j;
        float rot = (d < 32) ? -rowbuf[i0 + j + 32] : rowbuf[i0 + j - 32];
        o[j] = rowbuf[i0 + j] * cosb[s*ROTD + d] + rot * sinb[s*ROTD + d];
      }
    } else {
      #pragma unroll
      for (int j = 0; j < 8; ++j) o[j] = rowbuf[i0 + j];
    }
    uint4 r;
    r.x = (u32)f2bf_fast(o[0]*SL) | ((u32)f2bf_fast(o[1]*SL) << 16);
    r.y = (u32)f2bf_fast(o[2]*SL) | ((u32)f2bf_fast(o[3]*SL) << 16);
    r.z = (u32)f2bf_fast(o[4]*SL) | ((u32)f2bf_fast(o[5]*SL) << 16);
    r.w = (u32)f2bf_fast(o[6]*SL) | ((u32)f2bf_fast(o[7]*SL) << 16);
    *(uint4*)(Qo + ((size_t)hh * S_LEN + s) * HDIM + d0) = r;
  }

  const u16* kbase = base + HIDN;
  float y0, y1;
  { u32 v = *(const u32*)(kbase + t * 2); y0 = bf2f((u16)(v & 0xffffu)); y1 = bf2f((u16)(v >> 16)); }
  float ss2 = y0*y0 + y1*y1;
  #pragma unroll
  for (int m = 1; m < 64; m <<= 1) ss2 += __shfl_xor(ss2, m);
  __syncthreads();
  if (lane == 0) red[wave] = ss2;
  __syncthreads();
  float rs2 = rsqrtf((red[0]+red[1]+red[2]+red[3]) * (1.0f / 512.0f) + 1e-6f);
  rowbuf[t*2]     = y0 * rs2 * kw[t*2];
  rowbuf[t*2 + 1] = y1 * rs2 * kw[t*2 + 1];
  __syncthreads();
  {
    int i0 = t * 2, d0 = i0 & (HDIM - 1), hh = i0 >> 7;
    float o0, o1;
    if (d0 < ROTD) {
      float r0 = (d0 < 32) ? -rowbuf[i0 + 32] : rowbuf[i0 - 32];
      float r1 = (d0 + 1 < 32) ? -rowbuf[i0 + 1 + 32] : rowbuf[i0 + 1 - 32];
      o0 = rowbuf[i0]     * cosb[s*ROTD + d0]     + r0 * sinb[s*ROTD + d0];
      o1 = rowbuf[i0 + 1] * cosb[s*ROTD + d0 + 1] + r1 * sinb[s*ROTD + d0 + 1];
    } else { o0 = rowbuf[i0]; o1 = rowbuf[i0 + 1]; }
    u32 r = (u32)f2bf_fast(o0) | ((u32)f2bf_fast(o1) << 16);
    *(u32*)(Ko + ((size_t)hh * S_LEN + s) * HDIM + d0) = r;
  }
}

// ---------------- V transpose: qkv[S][3072] v-cols -> Vt[NKV][HD][S] --------
__global__ __launch_bounds__(256) void vtrans(const u16* __restrict__ qkv,
                                              u16* __restrict__ Vt) {
  const int sb = blockIdx.x * 64, db = blockIdx.y * 64, kvh = blockIdx.z;
  __shared__ u16 tile[64][72];
  const int t = threadIdx.x;
  {
    int r = t >> 2, cc = (t & 3) * 16;
    const u16* src = qkv + (size_t)(sb + r) * QKVN + 2560 + kvh * HDIM + db + cc;
    *(uint4*)&tile[r][cc]     = *(const uint4*)(src);
    *(uint4*)&tile[r][cc + 8] = *(const uint4*)(src + 8);
  }
  __syncthreads();
  {
    int d = t >> 2, sc = (t & 3) * 16;
    u16 tmp[16];
    #pragma unroll
    for (int j = 0; j < 16; ++j) tmp[j] = tile[sc + j][d];
    u16* dst = Vt + ((size_t)kvh * HDIM + db + d) * S_LEN + sb + sc;
    *(uint4*)dst       = *(uint4*)&tmp[0];
    *(uint4*)(dst + 8) = *(uint4*)&tmp[8];
  }
}

// ---------------- causal GQA flash attention (v7, restored from R12/R13) ----
// V LDS staging is load-bearing (R14 lesson): gl2lds converts L2 latency
// (~200-900cyc) to LDS latency (~120cyc) once per block-tile with no VGPR
// round-trip; per-wave direct L2 reads re-pay full latency every tile and
// sit behind K staging in the in-order vmcnt queue.
__global__ __launch_bounds__(256, 2) void attn_fwd(const u16* __restrict__ Q,
                                                   const u16* __restrict__ K,
                                                   const u16* __restrict__ Vt,
                                                   u16* __restrict__ O) {
  const int n    = blockIdx.x;
  const int slot = n & 7, kq = n >> 3;             // kq 0..63
  const int kvh  = slot >> 1;                      // XCD affinity: 2 slots/kvh
  const int h    = kvh * 4 + (slot & 1) * 2 + (kq & 1);
  const int p    = kq >> 1;                        // mirror-pair index 0..31
  const int tid = threadIdx.x, wave = tid >> 6, lane = tid & 63;
  const int rh   = wave & 1;                       // row-half of the q tile
  const int kvh2 = wave >> 1;                      // kv-half of the kv tile
  __shared__ u16 Ks[2][64][128];                   // 32KB (dbuf K)
  __shared__ u16 Vs[2][128][64];                   // 32KB (dbuf V)
  __shared__ u16 Ps[2][32][64];                    //  8KB (per row-half)

  const u16* gKb[4]; const u16* gVb[4];
  #pragma unroll
  for (int i = 0; i < 4; ++i) {
    int cc = wave * 4 + i;
    int rk = cc * 4 + (lane >> 4);
    gKb[i] = K + ((size_t)kvh * S_LEN + rk) * HDIM + ((lane & 15) ^ (rk & 7)) * 8;
    int rv = cc * 8 + (lane >> 3);
    gVb[i] = Vt + ((size_t)kvh * HDIM + rv) * S_LEN + ((lane & 7) ^ (rv & 7)) * 8;
  }
  auto stage = [&](int buf, int kvb) {
    #pragma unroll
    for (int i = 0; i < 4; ++i) {
      int cc = wave * 4 + i;
      gl2lds16(gKb[i] + (size_t)kvb * HDIM, &Ks[buf][cc * 4][0]);
      gl2lds16(gVb[i] + kvb,                &Vs[buf][cc * 8][0]);
    }
  };

  int offv[4];
  #pragma unroll
  for (int kk = 0; kk < 4; ++kk)
    offv[kk] = (kk * 64 + (lane >> 4) * 16) ^ ((lane & 7) << 4);
  const char* ksB = (const char*)Ks + kvh2 * 8192 + (lane & 15) * 256;
  const char* vsB = (const char*)Vs + (lane & 15) * 128;
  const char* psB = (const char*)Ps + rh * 4096 + (lane & 15) * 128;
  char*       pwB = (char*)Ps + rh * 4096;
  const int   lx2 = (lane & 15) * 2;
  const int   vko = offv[kvh2];                    // vf/pf col offset (kv half)

  stage(0, 0);                                     // prologue: job0 tile0
  __syncthreads();
  int cur = 0;

  for (int job = 0; job < 2; ++job) {
    const int qb = job ? (63 - p) : p;
    const int ntiles = qb + 1;
    const int qg0 = qb * 64 + rh * 32 + (lane >> 4) * 4;  // + qm*16 + r = q row

    bf16x8 qf[2][4];
    #pragma unroll
    for (int qm = 0; qm < 2; ++qm) {
      const u16* qptr = Q + ((size_t)h * S_LEN + qb * 64 + rh * 32 + qm * 16 + (lane & 15)) * HDIM
                        + (lane >> 4) * 8;
      #pragma unroll
      for (int kk = 0; kk < 4; ++kk) qf[qm][kk] = *(const bf16x8*)(qptr + kk * 32);
    }

    float lsum[2][4];
    #pragma unroll
    for (int qm = 0; qm < 2; ++qm)
      #pragma unroll
      for (int r = 0; r < 4; ++r) lsum[qm][r] = 0.f;
    f32x4 o[2][8];
    #pragma unroll
    for (int qm = 0; qm < 2; ++qm)
      #pragma unroll
      for (int i = 0; i < 8; ++i) { f32x4 z = {0.f,0.f,0.f,0.f}; o[qm][i] = z; }

    for (int kt = 0; kt < ntiles; ++kt) {
      if (kt + 1 < ntiles)      stage(cur ^ 1, (kt + 1) * 64);
      else if (job == 0)        stage(cur ^ 1, 0);

      const int bufo = cur << 14;
      const bool diag = (kt == ntiles - 1);

      if (!(diag && kvh2 == 1 && rh == 0)) {
        f32x4 sc[2][2];
        #pragma unroll
        for (int qm = 0; qm < 2; ++qm)
          #pragma unroll
          for (int i = 0; i < 2; ++i) { f32x4 z = {0.f,0.f,0.f,0.f}; sc[qm][i] = z; }
        __builtin_amdgcn_s_setprio(1);
        #pragma unroll
        for (int kk = 0; kk < 4; ++kk)
          #pragma unroll
          for (int nf = 0; nf < 2; ++nf) {
            bf16x8 kf = *(const bf16x8*)(ksB + bufo + nf * 4096 + offv[kk]);
            sc[0][nf] = mfma_bf16(qf[0][kk], kf, sc[0][nf]);
            sc[1][nf] = mfma_bf16(qf[1][kk], kf, sc[1][nf]);
          }
        __builtin_amdgcn_s_setprio(0);

        if (diag) {
          const int kvb = kt * 64;
          #pragma unroll
          for (int qm = 0; qm < 2; ++qm)
            #pragma unroll
            for (int nf = 0; nf < 2; ++nf) {
              int col = kvb + kvh2 * 32 + nf * 16 + (lane & 15);
              #pragma unroll
              for (int r = 0; r < 4; ++r) {
                float e = __builtin_amdgcn_exp2f(sc[qm][nf][r]);
                e = (col <= qg0 + qm * 16 + r) ? e : 0.f;
                sc[qm][nf][r] = e;
                lsum[qm][r] += e;
              }
            }
        } else {
          #pragma unroll
          for (int qm = 0; qm < 2; ++qm)
            #pragma unroll
            for (int nf = 0; nf < 2; ++nf)
              #pragma unroll
              for (int r = 0; r < 4; ++r) {
                float e = __builtin_amdgcn_exp2f(sc[qm][nf][r]);
                sc[qm][nf][r] = e;
                lsum[qm][r] += e;
              }
        }

        #pragma unroll
        for (int qm = 0; qm < 2; ++qm)
          #pragma unroll
          for (int nf = 0; nf < 2; ++nf)
            #pragma unroll
            for (int r = 0; r < 4; ++r) {
              int prow = qm * 16 + (lane >> 4) * 4 + r;
              int bcol = (kvh2 * 64 + nf * 32 + lx2) ^ ((prow & 7) << 4);
              *(u16*)(pwB + prow * 128 + bcol) = f2bf_fast(sc[qm][nf][r]);
            }

        bf16x8 pf0, pf1;
        pf0 = *(const bf16x8*)(psB + vko);
        pf1 = *(const bf16x8*)(psB + 2048 + vko);
        __builtin_amdgcn_s_setprio(1);
        #pragma unroll
        for (int nf2 = 0; nf2 < 8; ++nf2) {
          bf16x8 vf = *(const bf16x8*)(vsB + bufo + nf2 * 2048 + vko);
          o[0][nf2] = mfma_bf16(pf0, vf, o[0][nf2]);
          o[1][nf2] = mfma_bf16(pf1, vf, o[1][nf2]);
        }
        __builtin_amdgcn_s_setprio(0);
      }

      __syncthreads();
      cur ^= 1;
    }

    // ---- cross-kv-half combine (partials exactly additive) ----
    {
      f32x4* scr = (f32x4*)((rh == 0) ? (char*)Ks + (cur ^ 1) * 16384
                                      : (char*)Vs + (cur ^ 1) * 16384);
      float* lsc = (float*)Ps;
      if (kvh2 == 1) {
        #pragma unroll
        for (int qm = 0; qm < 2; ++qm)
          #pragma unroll
          for (int nf2 = 0; nf2 < 8; ++nf2)
            scr[(qm * 8 + nf2) * 64 + lane] = o[qm][nf2];
        #pragma unroll
        for (int qm = 0; qm < 2; ++qm)
          #pragma unroll
          for (int r = 0; r < 4; ++r)
            lsc[rh * 512 + (qm * 4 + r) * 64 + lane] = lsum[qm][r];
      }
      __syncthreads();
      if (kvh2 == 0) {
        #pragma unroll
        for (int qm = 0; qm < 2; ++qm)
          #pragma unroll
          for (int nf2 = 0; nf2 < 8; ++nf2)
            o[qm][nf2] += scr[(qm * 8 + nf2) * 64 + lane];
        #pragma unroll
        for (int qm = 0; qm < 2; ++qm)
          #pragma unroll
          for (int r = 0; r < 4; ++r)
            lsum[qm][r] += lsc[rh * 512 + (qm * 4 + r) * 64 + lane];

        #pragma unroll
        for (int qm = 0; qm < 2; ++qm)
          #pragma unroll
          for (int r = 0; r < 4; ++r) {
            float lt = lsum[qm][r];
            #pragma unroll
            for (int m = 1; m < 16; m <<= 1) lt += __shfl_xor(lt, m);
            float inv = 1.f / lt;
            int srow = qg0 + qm * 16 + r;
            #pragma unroll
            for (int nf2 = 0; nf2 < 8; ++nf2) {
              int col = h * HDIM + nf2 * 16 + (lane & 15);
              O[(size_t)srow * HIDN + col] = f2bf_fast(o[qm][nf2][r] * inv);
            }
          }
      }
      __syncthreads();
    }
  }
}

// ---------------- launch -----------------------------------------------------
extern "C" void kernel_launch(void* const* d_in, const int* in_sizes, int n_in,
                              void* d_out, int out_size, void* d_ws, size_t ws_size,
                              hipStream_t stream) {
  (void)in_sizes; (void)n_in; (void)out_size; (void)ws_size;
  const float* h    = (const float*)d_in[0];
  const float* cosb = (const float*)d_in[1];
  const float* sinb = (const float*)d_in[2];
  const float* Wq   = (const float*)d_in[3];
  const float* Wk   = (const float*)d_in[4];
  const float* Wv   = (const float*)d_in[5];
  const float* Wo   = (const float*)d_in[6];
  const float* qw   = (const float*)d_in[7];
  const float* kw   = (const float*)d_in[8];
  float* out = (float*)d_out;

  char* ws = (char*)d_ws;
  u16* hbf  = (u16*)(ws);
  u16* Kb   = (u16*)(ws + (16u << 20));
  u16* Vtb  = (u16*)(ws + (20u << 20));
  u16* wqkv = (u16*)(ws + (24u << 20));
  u16* Qb   = (u16*)(ws + (24u << 20));
  u16* qkvb = (u16*)(ws + (40u << 20));
  u16* wob  = (u16*)(ws + (40u << 20));

  cvt4_f32_bf16<<<7168, 256, 0, stream>>>(h, Wq, Wk, Wv, hbf, wqkv);

  gemm_big<192, 3, true><<<dim3(16, 16), 512, 0, stream>>>(hbf, wqkv, qkvb,
                                                           4096, 3072, 2048);

  norm_rope<<<4096, 256, 0, stream>>>(qkvb, cosb, sinb, qw, kw, Qb, Kb);
  vtrans<<<dim3(64, 2, 4), 256, 0, stream>>>(qkvb, Vtb);

  cvt_f32_bf16<<<2048, 256, 0, stream>>>(Wo, wob);

  attn_fwd<<<dim3(512), 256, 0, stream>>>(Qb, Kb, Vtb, hbf);

  gemm_big<128, 2, false><<<dim3(16, 16), 512, 0, stream>>>(hbf, wob, out,
                                                            4096, 2048, 2048);
}

// Round 16
// 231.717 us; speedup vs baseline: 1.2454x; 1.0385x over previous
//
#include <hip/hip_runtime.h>

typedef unsigned short u16;
typedef unsigned int   u32;
typedef __bf16 bf16x8 __attribute__((ext_vector_type(8)));
typedef float  f32x4  __attribute__((ext_vector_type(4)));

#define S_LEN 4096
#define HIDN  2048
#define NHEAD 16
#define NKVH  4
#define HDIM  128
#define ROTD  64
#define QKVN  3072

__device__ __forceinline__ u16 f2bf_fast(float f) {
  union { __bf16 b; u16 u; } cv; cv.b = (__bf16)f; return cv.u;   // v_cvt hw RNE
}
__device__ __forceinline__ float bf2f(u16 u) {
  union { u32 u; float f; } v; v.u = ((u32)u) << 16; return v.f;
}
__device__ __forceinline__ void gl2lds16(const u16* g, u16* l) {
  __builtin_amdgcn_global_load_lds((const __attribute__((address_space(1))) void*)g,
                                   (__attribute__((address_space(3))) void*)l, 16, 0, 0);
}
__device__ __forceinline__ f32x4 mfma_bf16(bf16x8 a, bf16x8 b, f32x4 c) {
  return __builtin_amdgcn_mfma_f32_16x16x32_bf16(a, b, c, 0, 0, 0);
}
template <int N> __device__ __forceinline__ void vmwait() {
  if constexpr (N == 5)      asm volatile("s_waitcnt vmcnt(5)" ::: "memory");
  else if constexpr (N == 4) asm volatile("s_waitcnt vmcnt(4)" ::: "memory");
  else                       asm volatile("s_waitcnt vmcnt(0)" ::: "memory");
}

// ---------------- fused f32 -> bf16 convert: h | Wq | Wk | Wv (one launch) --
__global__ __launch_bounds__(256) void cvt4_f32_bf16(const float* __restrict__ h,
                                                     const float* __restrict__ Wq,
                                                     const float* __restrict__ Wk,
                                                     const float* __restrict__ Wv,
                                                     u16* __restrict__ hbf,
                                                     u16* __restrict__ wqkv) {
  const int b = blockIdx.x;
  const float* src; u16* dst;
  if (b < 4096)      { src = h  + (size_t)b * 2048;           dst = hbf  + (size_t)b * 2048; }
  else if (b < 6144) { src = Wq + (size_t)(b - 4096) * 2048;  dst = wqkv + (size_t)(b - 4096) * 2048; }
  else if (b < 6656) { src = Wk + (size_t)(b - 6144) * 2048;  dst = wqkv + 4194304u + (size_t)(b - 6144) * 2048; }
  else               { src = Wv + (size_t)(b - 6656) * 2048;  dst = wqkv + 5242880u + (size_t)(b - 6656) * 2048; }
  size_t i = (size_t)threadIdx.x * 8;
  float4 a = *(const float4*)(src + i);
  float4 c = *(const float4*)(src + i + 4);
  uint4 r;
  r.x = (u32)f2bf_fast(a.x) | ((u32)f2bf_fast(a.y) << 16);
  r.y = (u32)f2bf_fast(a.z) | ((u32)f2bf_fast(a.w) << 16);
  r.z = (u32)f2bf_fast(c.x) | ((u32)f2bf_fast(c.y) << 16);
  r.w = (u32)f2bf_fast(c.z) | ((u32)f2bf_fast(c.w) << 16);
  *(uint4*)(dst + i) = r;
}

// ---------------- plain f32 -> bf16 convert (Wo, after qkvb is dead) --------
__global__ __launch_bounds__(256) void cvt_f32_bf16(const float* __restrict__ in,
                                                    u16* __restrict__ out) {
  size_t i = ((size_t)blockIdx.x * 256 + threadIdx.x) * 8;
  float4 a = *(const float4*)(in + i);
  float4 b = *(const float4*)(in + i + 4);
  uint4 r;
  r.x = (u32)f2bf_fast(a.x) | ((u32)f2bf_fast(a.y) << 16);
  r.y = (u32)f2bf_fast(a.z) | ((u32)f2bf_fast(a.w) << 16);
  r.z = (u32)f2bf_fast(b.x) | ((u32)f2bf_fast(b.y) << 16);
  r.w = (u32)f2bf_fast(b.z) | ((u32)f2bf_fast(b.w) << 16);
  *(uint4*)(out + i) = r;
}

// ---------------- GEMM v4: C[M,N] = A[M,K]*B[N,K]^T, 2 blocks/CU ------------
// BM=128 x BN (192/128), BK=64, 8 waves (2M x 4N), per-wave 64 x BN/4.
// R16 change: BM 256 -> 128 so LDS = 80/64 KB -> EXACTLY 2 blocks/CU
// (grid 32x16 = 512 = 2/CU, zero remainder). Rationale (m114): at 1
// block/CU every barrier/vmcnt wait stalls the whole CU; a co-resident
// block backfills those stalls (implicit wave-level overlap) -- the same
// mechanism that makes the m97 family fast without explicit pipelining.
// Keeps: gl2lds width-16 staging with pre-swizzled source, XOR-swizzled
// ds_read (row&7 == l8 invariant: all row bases are multiples of 8),
// barrier-pair phases (2 per K-tile), 2-tile lookahead, counted vmcnt.
template <int BN, int NB, bool BF16OUT>
__global__ __launch_bounds__(512, 4) void gemm_big(const u16* __restrict__ A,
                                                   const u16* __restrict__ Bm,
                                                   void* __restrict__ Cp,
                                                   int M, int N, int K) {
  constexpr int WNC = BN / 4;           // per-wave N cols (48 or 32)
  constexpr int NF  = WNC / 16;         // N fragments (3 or 2)
  constexpr int ASZ = 128 * 128;        // A bytes per buffer (16KB)
  constexpr int BUF = ASZ + BN * 128;   // one K-tile buffer (A+B)
  constexpr int LOADS = 2 + NB;         // gl2lds per wave per K-tile
  __shared__ __align__(1024) char lds[2 * BUF];

  const int tid = threadIdx.x, wave = tid >> 6, lane = tid & 63;
  const int wm = wave >> 2, wn = wave & 3;
  const int row0 = blockIdx.x * 128, col0 = blockIdx.y * BN;
  const int l8 = lane >> 3, l7 = lane & 7;
  const int T = K >> 6;

  // staging: wave stages A rows wave*16..+15 (2 loads x 8 rows x 128B) and
  // B rows wave*(BN/8).. (NB loads). Source col pre-swizzled: slot = l7^l8.
  const u16* gA[2]; const u16* gB[NB];
  u16* ldsA[2]; u16* ldsB[NB];
  #pragma unroll
  for (int i = 0; i < 2; ++i) {
    gA[i]  = A + (size_t)(row0 + wave * 16 + i * 8 + l8) * K + (l7 ^ l8) * 8;
    ldsA[i] = (u16*)(lds + wave * 2048 + i * 1024);
  }
  #pragma unroll
  for (int i = 0; i < NB; ++i) {
    gB[i]  = Bm + (size_t)(col0 + wave * (BN / 8) + i * 8 + l8) * K + (l7 ^ l8) * 8;
    ldsB[i] = (u16*)(lds + ASZ + wave * (BN * 16) + i * 1024);
  }
  auto stage = [&](int buf, int t) {
    const size_t ko = (size_t)t * 64;
    #pragma unroll
    for (int i = 0; i < 2; ++i)
      gl2lds16(gA[i] + ko, (u16*)((char*)ldsA[i] + buf * BUF));
    #pragma unroll
    for (int i = 0; i < NB; ++i)
      gl2lds16(gB[i] + ko, (u16*)((char*)ldsB[i] + buf * BUF));
  };

  // swizzled ds_read col offsets (k-half 0/1); frag row byte bases
  const int colx0 = (((lane >> 4))     ^ l7) * 16;
  const int colx1 = ((4 + (lane >> 4)) ^ l7) * 16;
  const char* aB = lds + (wm * 64 + (lane & 15)) * 128;
  const char* bB = lds + ASZ + (wn * WNC + (lane & 15)) * 128;

  f32x4 acc[4][NF];
  #pragma unroll
  for (int i = 0; i < 4; ++i)
    #pragma unroll
    for (int j = 0; j < NF; ++j) { f32x4 z = {0.f,0.f,0.f,0.f}; acc[i][j] = z; }

  stage(0, 0);
  stage(1, 1);
  vmwait<LOADS>();                       // tile 0 landed (tile 1 in flight)
  __builtin_amdgcn_s_barrier();

  for (int t = 0; t < T; ++t) {
    const int bo = (t & 1) * BUF;
    #pragma unroll
    for (int kh = 0; kh < 2; ++kh) {
      const int cx = kh ? colx1 : colx0;
      bf16x8 bfr[NF];
      #pragma unroll
      for (int nf = 0; nf < NF; ++nf)
        bfr[nf] = *(const bf16x8*)(bB + bo + nf * 2048 + cx);
      bf16x8 af[4];
      #pragma unroll
      for (int mf = 0; mf < 4; ++mf)
        af[mf] = *(const bf16x8*)(aB + bo + mf * 2048 + cx);
      __builtin_amdgcn_s_barrier();
      asm volatile("s_waitcnt lgkmcnt(0)" ::: "memory");
      __builtin_amdgcn_s_setprio(1);
      #pragma unroll
      for (int mf = 0; mf < 4; ++mf)
        #pragma unroll
        for (int nf = 0; nf < NF; ++nf)
          acc[mf][nf] = mfma_bf16(af[mf], bfr[nf], acc[mf][nf]);
      __builtin_amdgcn_s_setprio(0);
      __builtin_amdgcn_s_barrier();
    }
    if (t + 2 < T) stage(t & 1, t + 2);
    if (t + 1 < T) {
      if (t + 2 < T) vmwait<LOADS>();    // tile t+1 landed; t+2 in flight
      else           vmwait<0>();        // tail drain
      __builtin_amdgcn_s_barrier();
    }
  }

  // epilogue: C/D layout row=(l>>4)*4+r, col=l&15 (m89-verified)
  const int mwv = row0 + wm * 64, nwv = col0 + wn * WNC;
  #pragma unroll
  for (int mf = 0; mf < 4; ++mf)
    #pragma unroll
    for (int nf = 0; nf < NF; ++nf)
      #pragma unroll
      for (int r = 0; r < 4; ++r) {
        int m = mwv + mf * 16 + (lane >> 4) * 4 + r;
        int n = nwv + nf * 16 + (lane & 15);
        float v = acc[mf][nf][r];
        if (BF16OUT) ((u16*)Cp)[(size_t)m * N + n] = f2bf_fast(v);
        else         ((float*)Cp)[(size_t)m * N + n] = v;
      }
}

// ---------------- fused RMSNorm (full row) + partial RoPE + head transpose --
__global__ __launch_bounds__(256) void norm_rope(const u16* __restrict__ qkv,
                                                 const float* __restrict__ cosb,
                                                 const float* __restrict__ sinb,
                                                 const float* __restrict__ qw,
                                                 const float* __restrict__ kw,
                                                 u16* __restrict__ Qo,
                                                 u16* __restrict__ Ko) {
  const int s = blockIdx.x, t = threadIdx.x;
  const int wave = t >> 6, lane = t & 63;
  const float SL = 0.08838834764831845f * 1.4426950408889634f;  // SCALE*log2e
  __shared__ float rowbuf[HIDN];
  __shared__ float red[4];
  const u16* base = qkv + (size_t)s * QKVN;

  float x[8];
  {
    uint4 v = *(const uint4*)(base + t * 8);
    u32 w4[4] = {v.x, v.y, v.z, v.w};
    #pragma unroll
    for (int j = 0; j < 4; ++j) {
      x[2*j]   = bf2f((u16)(w4[j] & 0xffffu));
      x[2*j+1] = bf2f((u16)(w4[j] >> 16));
    }
  }
  float ss = 0.f;
  #pragma unroll
  for (int j = 0; j < 8; ++j) ss += x[j] * x[j];
  #pragma unroll
  for (int m = 1; m < 64; m <<= 1) ss += __shfl_xor(ss, m);
  if (lane == 0) red[wave] = ss;
  __syncthreads();
  float rs = rsqrtf((red[0]+red[1]+red[2]+red[3]) * (1.0f / HIDN) + 1e-6f);
  #pragma unroll
  for (int j = 0; j < 8; ++j) rowbuf[t*8 + j] = x[j] * rs * qw[t*8 + j];
  __syncthreads();
  {
    int i0 = t * 8, d0 = i0 & (HDIM - 1), hh = i0 >> 7;
    float o[8];
    if (d0 < ROTD) {
      #pragma unroll
      for (int j = 0; j < 8; ++j) {
        int d = d0 + j;
        float rot = (d < 32) ? -rowbuf[i0 + j + 32] : rowbuf[i0 + j - 32];
        o[j] = rowbuf[i0 + j] * cosb[s*ROTD + d] + rot * sinb[s*ROTD + d];
      }
    } else {
      #pragma unroll
      for (int j = 0; j < 8; ++j) o[j] = rowbuf[i0 + j];
    }
    uint4 r;
    r.x = (u32)f2bf_fast(o[0]*SL) | ((u32)f2bf_fast(o[1]*SL) << 16);
    r.y = (u32)f2bf_fast(o[2]*SL) | ((u32)f2bf_fast(o[3]*SL) << 16);
    r.z = (u32)f2bf_fast(o[4]*SL) | ((u32)f2bf_fast(o[5]*SL) << 16);
    r.w = (u32)f2bf_fast(o[6]*SL) | ((u32)f2bf_fast(o[7]*SL) << 16);
    *(uint4*)(Qo + ((size_t)hh * S_LEN + s) * HDIM + d0) = r;
  }

  const u16* kbase = base + HIDN;
  float y0, y1;
  { u32 v = *(const u32*)(kbase + t * 2); y0 = bf2f((u16)(v & 0xffffu)); y1 = bf2f((u16)(v >> 16)); }
  float ss2 = y0*y0 + y1*y1;
  #pragma unroll
  for (int m = 1; m < 64; m <<= 1) ss2 += __shfl_xor(ss2, m);
  __syncthreads();
  if (lane == 0) red[wave] = ss2;
  __syncthreads();
  float rs2 = rsqrtf((red[0]+red[1]+red[2]+red[3]) * (1.0f / 512.0f) + 1e-6f);
  rowbuf[t*2]     = y0 * rs2 * kw[t*2];
  rowbuf[t*2 + 1] = y1 * rs2 * kw[t*2 + 1];
  __syncthreads();
  {
    int i0 = t * 2, d0 = i0 & (HDIM - 1), hh = i0 >> 7;
    float o0, o1;
    if (d0 < ROTD) {
      float r0 = (d0 < 32) ? -rowbuf[i0 + 32] : rowbuf[i0 - 32];
      float r1 = (d0 + 1 < 32) ? -rowbuf[i0 + 1 + 32] : rowbuf[i0 + 1 - 32];
      o0 = rowbuf[i0]     * cosb[s*ROTD + d0]     + r0 * sinb[s*ROTD + d0];
      o1 = rowbuf[i0 + 1] * cosb[s*ROTD + d0 + 1] + r1 * sinb[s*ROTD + d0 + 1];
    } else { o0 = rowbuf[i0]; o1 = rowbuf[i0 + 1]; }
    u32 r = (u32)f2bf_fast(o0) | ((u32)f2bf_fast(o1) << 16);
    *(u32*)(Ko + ((size_t)hh * S_LEN + s) * HDIM + d0) = r;
  }
}

// ---------------- V transpose: qkv[S][3072] v-cols -> Vt[NKV][HD][S] --------
__global__ __launch_bounds__(256) void vtrans(const u16* __restrict__ qkv,
                                              u16* __restrict__ Vt) {
  const int sb = blockIdx.x * 64, db = blockIdx.y * 64, kvh = blockIdx.z;
  __shared__ u16 tile[64][72];
  const int t = threadIdx.x;
  {
    int r = t >> 2, cc = (t & 3) * 16;
    const u16* src = qkv + (size_t)(sb + r) * QKVN + 2560 + kvh * HDIM + db + cc;
    *(uint4*)&tile[r][cc]     = *(const uint4*)(src);
    *(uint4*)&tile[r][cc + 8] = *(const uint4*)(src + 8);
  }
  __syncthreads();
  {
    int d = t >> 2, sc = (t & 3) * 16;
    u16 tmp[16];
    #pragma unroll
    for (int j = 0; j < 16; ++j) tmp[j] = tile[sc + j][d];
    u16* dst = Vt + ((size_t)kvh * HDIM + db + d) * S_LEN + sb + sc;
    *(uint4*)dst       = *(uint4*)&tmp[0];
    *(uint4*)(dst + 8) = *(uint4*)&tmp[8];
  }
}

// ---------------- causal GQA flash attention (v7, unchanged) ----------------
__global__ __launch_bounds__(256, 2) void attn_fwd(const u16* __restrict__ Q,
                                                   const u16* __restrict__ K,
                                                   const u16* __restrict__ Vt,
                                                   u16* __restrict__ O) {
  const int n    = blockIdx.x;
  const int slot = n & 7, kq = n >> 3;             // kq 0..63
  const int kvh  = slot >> 1;                      // XCD affinity: 2 slots/kvh
  const int h    = kvh * 4 + (slot & 1) * 2 + (kq & 1);
  const int p    = kq >> 1;                        // mirror-pair index 0..31
  const int tid = threadIdx.x, wave = tid >> 6, lane = tid & 63;
  const int rh   = wave & 1;                       // row-half of the q tile
  const int kvh2 = wave >> 1;                      // kv-half of the kv tile
  __shared__ u16 Ks[2][64][128];                   // 32KB (dbuf K)
  __shared__ u16 Vs[2][128][64];                   // 32KB (dbuf V)
  __shared__ u16 Ps[2][32][64];                    //  8KB (per row-half)

  const u16* gKb[4]; const u16* gVb[4];
  #pragma unroll
  for (int i = 0; i < 4; ++i) {
    int cc = wave * 4 + i;
    int rk = cc * 4 + (lane >> 4);
    gKb[i] = K + ((size_t)kvh * S_LEN + rk) * HDIM + ((lane & 15) ^ (rk & 7)) * 8;
    int rv = cc * 8 + (lane >> 3);
    gVb[i] = Vt + ((size_t)kvh * HDIM + rv) * S_LEN + ((lane & 7) ^ (rv & 7)) * 8;
  }
  auto stage = [&](int buf, int kvb) {
    #pragma unroll
    for (int i = 0; i < 4; ++i) {
      int cc = wave * 4 + i;
      gl2lds16(gKb[i] + (size_t)kvb * HDIM, &Ks[buf][cc * 4][0]);
      gl2lds16(gVb[i] + kvb,                &Vs[buf][cc * 8][0]);
    }
  };

  int offv[4];
  #pragma unroll
  for (int kk = 0; kk < 4; ++kk)
    offv[kk] = (kk * 64 + (lane >> 4) * 16) ^ ((lane & 7) << 4);
  const char* ksB = (const char*)Ks + kvh2 * 8192 + (lane & 15) * 256;
  const char* vsB = (const char*)Vs + (lane & 15) * 128;
  const char* psB = (const char*)Ps + rh * 4096 + (lane & 15) * 128;
  char*       pwB = (char*)Ps + rh * 4096;
  const int   lx2 = (lane & 15) * 2;
  const int   vko = offv[kvh2];                    // vf/pf col offset (kv half)

  stage(0, 0);                                     // prologue: job0 tile0
  __syncthreads();
  int cur = 0;

  for (int job = 0; job < 2; ++job) {
    const int qb = job ? (63 - p) : p;
    const int ntiles = qb + 1;
    const int qg0 = qb * 64 + rh * 32 + (lane >> 4) * 4;  // + qm*16 + r = q row

    bf16x8 qf[2][4];
    #pragma unroll
    for (int qm = 0; qm < 2; ++qm) {
      const u16* qptr = Q + ((size_t)h * S_LEN + qb * 64 + rh * 32 + qm * 16 + (lane & 15)) * HDIM
                        + (lane >> 4) * 8;
      #pragma unroll
      for (int kk = 0; kk < 4; ++kk) qf[qm][kk] = *(const bf16x8*)(qptr + kk * 32);
    }

    float lsum[2][4];
    #pragma unroll
    for (int qm = 0; qm < 2; ++qm)
      #pragma unroll
      for (int r = 0; r < 4; ++r) lsum[qm][r] = 0.f;
    f32x4 o[2][8];
    #pragma unroll
    for (int qm = 0; qm < 2; ++qm)
      #pragma unroll
      for (int i = 0; i < 8; ++i) { f32x4 z = {0.f,0.f,0.f,0.f}; o[qm][i] = z; }

    for (int kt = 0; kt < ntiles; ++kt) {
      if (kt + 1 < ntiles)      stage(cur ^ 1, (kt + 1) * 64);
      else if (job == 0)        stage(cur ^ 1, 0);

      const int bufo = cur << 14;
      const bool diag = (kt == ntiles - 1);

      if (!(diag && kvh2 == 1 && rh == 0)) {
        f32x4 sc[2][2];
        #pragma unroll
        for (int qm = 0; qm < 2; ++qm)
          #pragma unroll
          for (int i = 0; i < 2; ++i) { f32x4 z = {0.f,0.f,0.f,0.f}; sc[qm][i] = z; }
        __builtin_amdgcn_s_setprio(1);
        #pragma unroll
        for (int kk = 0; kk < 4; ++kk)
          #pragma unroll
          for (int nf = 0; nf < 2; ++nf) {
            bf16x8 kf = *(const bf16x8*)(ksB + bufo + nf * 4096 + offv[kk]);
            sc[0][nf] = mfma_bf16(qf[0][kk], kf, sc[0][nf]);
            sc[1][nf] = mfma_bf16(qf[1][kk], kf, sc[1][nf]);
          }
        __builtin_amdgcn_s_setprio(0);

        if (diag) {
          const int kvb = kt * 64;
          #pragma unroll
          for (int qm = 0; qm < 2; ++qm)
            #pragma unroll
            for (int nf = 0; nf < 2; ++nf) {
              int col = kvb + kvh2 * 32 + nf * 16 + (lane & 15);
              #pragma unroll
              for (int r = 0; r < 4; ++r) {
                float e = __builtin_amdgcn_exp2f(sc[qm][nf][r]);
                e = (col <= qg0 + qm * 16 + r) ? e : 0.f;
                sc[qm][nf][r] = e;
                lsum[qm][r] += e;
              }
            }
        } else {
          #pragma unroll
          for (int qm = 0; qm < 2; ++qm)
            #pragma unroll
            for (int nf = 0; nf < 2; ++nf)
              #pragma unroll
              for (int r = 0; r < 4; ++r) {
                float e = __builtin_amdgcn_exp2f(sc[qm][nf][r]);
                sc[qm][nf][r] = e;
                lsum[qm][r] += e;
              }
        }

        #pragma unroll
        for (int qm = 0; qm < 2; ++qm)
          #pragma unroll
          for (int nf = 0; nf < 2; ++nf)
            #pragma unroll
            for (int r = 0; r < 4; ++r) {
              int prow = qm * 16 + (lane >> 4) * 4 + r;
              int bcol = (kvh2 * 64 + nf * 32 + lx2) ^ ((prow & 7) << 4);
              *(u16*)(pwB + prow * 128 + bcol) = f2bf_fast(sc[qm][nf][r]);
            }

        bf16x8 pf0, pf1;
        pf0 = *(const bf16x8*)(psB + vko);
        pf1 = *(const bf16x8*)(psB + 2048 + vko);
        __builtin_amdgcn_s_setprio(1);
        #pragma unroll
        for (int nf2 = 0; nf2 < 8; ++nf2) {
          bf16x8 vf = *(const bf16x8*)(vsB + bufo + nf2 * 2048 + vko);
          o[0][nf2] = mfma_bf16(pf0, vf, o[0][nf2]);
          o[1][nf2] = mfma_bf16(pf1, vf, o[1][nf2]);
        }
        __builtin_amdgcn_s_setprio(0);
      }

      __syncthreads();
      cur ^= 1;
    }

    // ---- cross-kv-half combine (partials exactly additive) ----
    {
      f32x4* scr = (f32x4*)((rh == 0) ? (char*)Ks + (cur ^ 1) * 16384
                                      : (char*)Vs + (cur ^ 1) * 16384);
      float* lsc = (float*)Ps;
      if (kvh2 == 1) {
        #pragma unroll
        for (int qm = 0; qm < 2; ++qm)
          #pragma unroll
          for (int nf2 = 0; nf2 < 8; ++nf2)
            scr[(qm * 8 + nf2) * 64 + lane] = o[qm][nf2];
        #pragma unroll
        for (int qm = 0; qm < 2; ++qm)
          #pragma unroll
          for (int r = 0; r < 4; ++r)
            lsc[rh * 512 + (qm * 4 + r) * 64 + lane] = lsum[qm][r];
      }
      __syncthreads();
      if (kvh2 == 0) {
        #pragma unroll
        for (int qm = 0; qm < 2; ++qm)
          #pragma unroll
          for (int nf2 = 0; nf2 < 8; ++nf2)
            o[qm][nf2] += scr[(qm * 8 + nf2) * 64 + lane];
        #pragma unroll
        for (int qm = 0; qm < 2; ++qm)
          #pragma unroll
          for (int r = 0; r < 4; ++r)
            lsum[qm][r] += lsc[rh * 512 + (qm * 4 + r) * 64 + lane];

        #pragma unroll
        for (int qm = 0; qm < 2; ++qm)
          #pragma unroll
          for (int r = 0; r < 4; ++r) {
            float lt = lsum[qm][r];
            #pragma unroll
            for (int m = 1; m < 16; m <<= 1) lt += __shfl_xor(lt, m);
            float inv = 1.f / lt;
            int srow = qg0 + qm * 16 + r;
            #pragma unroll
            for (int nf2 = 0; nf2 < 8; ++nf2) {
              int col = h * HDIM + nf2 * 16 + (lane & 15);
              O[(size_t)srow * HIDN + col] = f2bf_fast(o[qm][nf2][r] * inv);
            }
          }
      }
      __syncthreads();
    }
  }
}

// ---------------- launch -----------------------------------------------------
extern "C" void kernel_launch(void* const* d_in, const int* in_sizes, int n_in,
                              void* d_out, int out_size, void* d_ws, size_t ws_size,
                              hipStream_t stream) {
  (void)in_sizes; (void)n_in; (void)out_size; (void)ws_size;
  const float* h    = (const float*)d_in[0];
  const float* cosb = (const float*)d_in[1];
  const float* sinb = (const float*)d_in[2];
  const float* Wq   = (const float*)d_in[3];
  const float* Wk   = (const float*)d_in[4];
  const float* Wv   = (const float*)d_in[5];
  const float* Wo   = (const float*)d_in[6];
  const float* qw   = (const float*)d_in[7];
  const float* kw   = (const float*)d_in[8];
  float* out = (float*)d_out;

  char* ws = (char*)d_ws;
  u16* hbf  = (u16*)(ws);
  u16* Kb   = (u16*)(ws + (16u << 20));
  u16* Vtb  = (u16*)(ws + (20u << 20));
  u16* wqkv = (u16*)(ws + (24u << 20));
  u16* Qb   = (u16*)(ws + (24u << 20));
  u16* qkvb = (u16*)(ws + (40u << 20));
  u16* wob  = (u16*)(ws + (40u << 20));

  cvt4_f32_bf16<<<7168, 256, 0, stream>>>(h, Wq, Wk, Wv, hbf, wqkv);

  gemm_big<192, 3, true><<<dim3(32, 16), 512, 0, stream>>>(hbf, wqkv, qkvb,
                                                           4096, 3072, 2048);

  norm_rope<<<4096, 256, 0, stream>>>(qkvb, cosb, sinb, qw, kw, Qb, Kb);
  vtrans<<<dim3(64, 2, 4), 256, 0, stream>>>(qkvb, Vtb);

  cvt_f32_bf16<<<2048, 256, 0, stream>>>(Wo, wob);

  attn_fwd<<<dim3(512), 256, 0, stream>>>(Qb, Kb, Vtb, hbf);

  gemm_big<128, 2, false><<<dim3(32, 16), 512, 0, stream>>>(hbf, wob, out,
                                                            4096, 2048, 2048);
}